// Round 5
// baseline (483.866 us; speedup 1.0000x reference)
//
#include <hip/hip_runtime.h>
#include <math.h>

#ifndef M_PI
#define M_PI 3.14159265358979323846
#endif

#define BB 64
#define HH 512
#define WW 512
#define NPIX (HH*WW)        // 262144
#define MED_K 131072u       // 1-indexed rank of (n-1)//2
#define MAGB 131584         // per-image magc floats: 257 cols * 512 rows (col-major)
#define BSTRIDE 264         // bufc row stride (float2), cols 0..256 valid
#define SS 520              // col staging stride (floats) per column
#define NFINE 8192          // fine mantissa bins (13 bits)

__device__ __forceinline__ float wredf(float v){
  #pragma unroll
  for (int o = 32; o > 0; o >>= 1) v += __shfl_down(v, o, 64);
  return v;
}
__device__ __forceinline__ float wred_min(float v){
  #pragma unroll
  for (int o = 32; o > 0; o >>= 1) v = fminf(v, __shfl_down(v, o, 64));
  return v;
}
__device__ __forceinline__ float wred_max(float v){
  #pragma unroll
  for (int o = 32; o > 0; o >>= 1) v = fmaxf(v, __shfl_down(v, o, 64));
  return v;
}
__device__ __forceinline__ unsigned wred_addu(unsigned v){
  #pragma unroll
  for (int o = 32; o > 0; o >>= 1) v += __shfl_down(v, o, 64);
  return v;
}
__device__ __forceinline__ float wred_add_all(float v){
  #pragma unroll
  for (int o = 32; o > 0; o >>= 1) v += __shfl_xor(v, o, 64);
  return v;
}

// ---------------- init: twiddles + scalar block ----------------
__global__ void init_kernel(float2* __restrict__ twg, unsigned* __restrict__ scal){
  int t = threadIdx.x;  // 256
  double a = -2.0 * M_PI * (double)t / 512.0;
  twg[t] = make_float2((float)cos(a), (float)sin(a));
  #pragma unroll
  for (int q = 0; q < 8; ++q){
    int w = t*8 + q;
    scal[w] = (w >= 64 && w < 128) ? 0xFFFFFFFFu : 0u;
  }
}

// Per-stage compact twiddle tables, concatenated in LDS:
// T_st[k] = twg[k << (9-st)], k in [0, 2^(st-1)), stage st = 2..9.
__device__ __forceinline__ void build_twid(float2* T, const float2* __restrict__ twg,
                                           int t, int nthr){
  for (int i = t; i < 510; i += nthr){
    int v = i + 2;
    int z = 31 - __clz(v);
    T[i] = twg[(v - (1 << z)) << (8 - z)];
  }
}

// One cross-lane butterfly stage in sign-folded FMA form.
__device__ __forceinline__ void bfly_stage(float (&re)[8], float (&im)[8],
                                           int d, float A, float B, float C, float D){
  #pragma unroll
  for (int r = 0; r < 8; ++r){
    float ore = __shfl_xor(re[r], d, 64);
    float oim = __shfl_xor(im[r], d, 64);
    float sre = re[r], sim = im[r];
    re[r] = A*sre + B*ore + C*sim + D*oim;
    im[r] = A*sim + B*oim - C*sre - D*ore;
  }
}

// Wave-resident 512-point radix-2 DIT FFT (see prior rounds for layout docs).
__device__ __forceinline__ void wave_fft512(float (&re)[8], float (&im)[8],
                                            const float2* T, int lane){
  { // stage 1
    float A = (lane & 1) ? -1.f : 1.f;
    #pragma unroll
    for (int r = 0; r < 8; ++r){
      float ore = __shfl_xor(re[r], 1, 64);
      float oim = __shfl_xor(im[r], 1, 64);
      re[r] = A*re[r] + ore;
      im[r] = A*im[r] + oim;
    }
  }
  #pragma unroll
  for (int st = 2; st <= 6; ++st){
    const int d = 1 << (st - 1);
    float2 w = T[((1 << (st - 1)) - 2) + (lane & (d - 1))];
    bool hi = (lane & d) != 0;
    float A = hi ? -w.x : 1.f;
    float B = hi ? 1.f : w.x;
    float C = hi ? w.y : 0.f;
    float D = hi ? 0.f : -w.y;
    bfly_stage(re, im, d, A, B, C, D);
  }
  { // stage 7
    float2 w = T[62 + lane];
    #pragma unroll
    for (int r = 0; r < 8; r += 2){
      float vr = w.x*re[r+1] - w.y*im[r+1];
      float vi = w.x*im[r+1] + w.y*re[r+1];
      float ur = re[r], ui = im[r];
      re[r]   = ur + vr; im[r]   = ui + vi;
      re[r+1] = ur - vr; im[r+1] = ui - vi;
    }
  }
  { // stage 8
    float2 w0 = T[126 + lane];
    float2 w1 = T[190 + lane];
    #pragma unroll
    for (int rb = 0; rb < 8; rb += 4){
      {
        float vr = w0.x*re[rb+2] - w0.y*im[rb+2];
        float vi = w0.x*im[rb+2] + w0.y*re[rb+2];
        float ur = re[rb], ui = im[rb];
        re[rb]   = ur + vr; im[rb]   = ui + vi;
        re[rb+2] = ur - vr; im[rb+2] = ui - vi;
      }
      {
        float vr = w1.x*re[rb+3] - w1.y*im[rb+3];
        float vi = w1.x*im[rb+3] + w1.y*re[rb+3];
        float ur = re[rb+1], ui = im[rb+1];
        re[rb+1] = ur + vr; im[rb+1] = ui + vi;
        re[rb+3] = ur - vr; im[rb+3] = ui - vi;
      }
    }
  }
  { // stage 9
    #pragma unroll
    for (int r = 0; r < 4; ++r){
      float2 w = T[254 + 64*r + lane];
      float vr = w.x*re[r+4] - w.y*im[r+4];
      float vi = w.x*im[r+4] + w.y*re[r+4];
      float ur = re[r], ui = im[r];
      re[r]   = ur + vr; im[r]   = ui + vi;
      re[r+4] = ur - vr; im[r+4] = ui - vi;
    }
  }
}

// ---------------- row FFT: contiguous loads + shfl bit-reversal ----------------
__global__ __launch_bounds__(256) void row_fft_kernel(const float* __restrict__ x,
                                                      const float2* __restrict__ twg,
                                                      float2* __restrict__ out){
  __shared__ float2 T[510];
  int t = threadIdx.x;
  build_twid(T, twg, t, 256);
  __syncthreads();
  int lane = t & 63, wv = t >> 6;
  int pair = blockIdx.x*4 + wv;        // b*256 + hp
  int b = pair >> 8, hp = pair & 255;
  int c0 = lane << 3;
  const float* p0 = x + (size_t)b*3*NPIX + (size_t)(2*hp)*WW + c0;
  const float* p1 = p0 + WW;
  float4 ra0 = *(const float4*)(p0);          float4 ra1 = *(const float4*)(p0+4);
  float4 ga0 = *(const float4*)(p0+NPIX);     float4 ga1 = *(const float4*)(p0+NPIX+4);
  float4 ba0 = *(const float4*)(p0+2*NPIX);   float4 ba1 = *(const float4*)(p0+2*NPIX+4);
  float4 rb0 = *(const float4*)(p1);          float4 rb1 = *(const float4*)(p1+4);
  float4 gb0 = *(const float4*)(p1+NPIX);     float4 gb1 = *(const float4*)(p1+NPIX+4);
  float4 bb0 = *(const float4*)(p1+2*NPIX);   float4 bb1 = *(const float4*)(p1+2*NPIX+4);
  float g0[8] = {0.299f*ra0.x + 0.587f*ga0.x + 0.114f*ba0.x,
                 0.299f*ra0.y + 0.587f*ga0.y + 0.114f*ba0.y,
                 0.299f*ra0.z + 0.587f*ga0.z + 0.114f*ba0.z,
                 0.299f*ra0.w + 0.587f*ga0.w + 0.114f*ba0.w,
                 0.299f*ra1.x + 0.587f*ga1.x + 0.114f*ba1.x,
                 0.299f*ra1.y + 0.587f*ga1.y + 0.114f*ba1.y,
                 0.299f*ra1.z + 0.587f*ga1.z + 0.114f*ba1.z,
                 0.299f*ra1.w + 0.587f*ga1.w + 0.114f*ba1.w};
  float g1[8] = {0.299f*rb0.x + 0.587f*gb0.x + 0.114f*bb0.x,
                 0.299f*rb0.y + 0.587f*gb0.y + 0.114f*bb0.y,
                 0.299f*rb0.z + 0.587f*gb0.z + 0.114f*bb0.z,
                 0.299f*rb0.w + 0.587f*gb0.w + 0.114f*bb0.w,
                 0.299f*rb1.x + 0.587f*gb1.x + 0.114f*bb1.x,
                 0.299f*rb1.y + 0.587f*gb1.y + 0.114f*bb1.y,
                 0.299f*rb1.z + 0.587f*gb1.z + 0.114f*bb1.z,
                 0.299f*rb1.w + 0.587f*gb1.w + 0.114f*bb1.w};
  int src = (int)(__brev((unsigned)lane) >> 26);   // rev6(lane)
  float re[8], im[8];
  re[0] = __shfl(g0[0], src, 64); re[1] = __shfl(g0[4], src, 64);
  re[2] = __shfl(g0[2], src, 64); re[3] = __shfl(g0[6], src, 64);
  re[4] = __shfl(g0[1], src, 64); re[5] = __shfl(g0[5], src, 64);
  re[6] = __shfl(g0[3], src, 64); re[7] = __shfl(g0[7], src, 64);
  im[0] = __shfl(g1[0], src, 64); im[1] = __shfl(g1[4], src, 64);
  im[2] = __shfl(g1[2], src, 64); im[3] = __shfl(g1[6], src, 64);
  im[4] = __shfl(g1[1], src, 64); im[5] = __shfl(g1[5], src, 64);
  im[6] = __shfl(g1[3], src, 64); im[7] = __shfl(g1[7], src, 64);
  wave_fft512(re, im, T, lane);
  int row0 = (b << 9) + 2*hp;
  float2* o0 = out + (size_t)row0*BSTRIDE;
  float2* o1 = o0 + BSTRIDE;
  int srcl = (64 - lane) & 63;
  float p4r = __shfl(re[4], srcl, 64), p4i = __shfl(im[4], srcl, 64);
  float p5r = __shfl(re[5], srcl, 64), p5i = __shfl(im[5], srcl, 64);
  float p6r = __shfl(re[6], srcl, 64), p6i = __shfl(im[6], srcl, 64);
  float p7r = __shfl(re[7], srcl, 64), p7i = __shfl(im[7], srcl, 64);
  bool l0 = (lane == 0);
  {
    float zr = re[0], zi = im[0];
    float wr = l0 ? re[0] : p7r, wi = l0 ? im[0] : p7i;
    o0[lane] = make_float2(0.5f*(zr + wr), 0.5f*(zi - wi));
    o1[lane] = make_float2(0.5f*(zi + wi), 0.5f*(wr - zr));
  }
  {
    float zr = re[1], zi = im[1];
    float wr = l0 ? re[7] : p6r, wi = l0 ? im[7] : p6i;
    int k = lane + 64;
    o0[k] = make_float2(0.5f*(zr + wr), 0.5f*(zi - wi));
    o1[k] = make_float2(0.5f*(zi + wi), 0.5f*(wr - zr));
  }
  {
    float zr = re[2], zi = im[2];
    float wr = l0 ? re[6] : p5r, wi = l0 ? im[6] : p5i;
    int k = lane + 128;
    o0[k] = make_float2(0.5f*(zr + wr), 0.5f*(zi - wi));
    o1[k] = make_float2(0.5f*(zi + wi), 0.5f*(wr - zr));
  }
  {
    float zr = re[3], zi = im[3];
    float wr = l0 ? re[5] : p4r, wi = l0 ? im[5] : p4i;
    int k = lane + 192;
    o0[k] = make_float2(0.5f*(zr + wr), 0.5f*(zi - wi));
    o1[k] = make_float2(0.5f*(zi + wi), 0.5f*(wr - zr));
  }
  if (l0){
    float zr = re[4], zi = im[4];
    o0[256] = make_float2(zr, 0.f);
    o1[256] = make_float2(zi, 0.f);
  }
}

// ---------------- col FFT: wave-per-column register FFT + fused stats ----------------
__global__ __launch_bounds__(512) void col_fft_kernel(const float2* __restrict__ in,
    const float2* __restrict__ twg,
    float* __restrict__ magc,
    unsigned* __restrict__ dmax, unsigned* __restrict__ dmin,
    double* __restrict__ sum, double* __restrict__ sumsq, double* __restrict__ qsum,
    unsigned* __restrict__ hist1)
{
  __shared__ float st_re[8*SS];
  __shared__ float st_im[8*SS];
  __shared__ float2 T[510];
  __shared__ unsigned h[8*256];       // per-wave privatized exponent histogram
  __shared__ float buff[8][8];
  int t = threadIdx.x;
  int lane = t & 63, wv = t >> 6;
  build_twid(T, twg, t, 512);
  for (int i = t; i < 2048; i += 512) h[i] = 0u;
  int b = blockIdx.x / 33;
  int j0 = (blockIdx.x % 33) << 3;
  const float2* base = in + (size_t)b * (size_t)(512*BSTRIDE);
  #pragma unroll
  for (int it = 0; it < 8; ++it){
    int idx = t + (it << 9);
    int e = idx >> 3, jj = idx & 7;
    float2 v = base[(size_t)e*BSTRIDE + j0 + jj];
    int se = e ^ (e >> 3);
    st_re[jj*SS + se] = v.x;
    st_im[jj*SS + se] = v.y;
  }
  __syncthreads();
  int j = j0 + wv;
  if (j <= 256){
    int K = (int)(__brev((unsigned)lane) >> 26);   // rev6(lane)
    const int rv3[8] = {0,4,2,6,1,5,3,7};
    float re[8], im[8];
    #pragma unroll
    for (int r = 0; r < 8; ++r){
      int e = 8*K + rv3[r];
      int se = e ^ K;
      re[r] = st_re[wv*SS + se];
      im[r] = st_im[wv*SS + se];
    }
    wave_fft512(re, im, T, lane);
    unsigned wu = (j == 0 || j == 256) ? 1u : 2u;
    float* mo = magc + (size_t)b*MAGB + (size_t)j*512;
    unsigned* hw = h + (wv << 8);
    float lsum=0.f, lsq=0.f;
    float lq[4] = {0.f, 0.f, 0.f, 0.f};
    float lmn = 3.4e38f, lmx = 0.f;
    const int QA[8]  = {2,2,3,3,0,0,1,1};
    const int QBM[8] = {1,1,0,0,3,3,2,2};
    #pragma unroll
    for (int r = 0; r < 8; ++r){
      float m = sqrtf(re[r]*re[r] + im[r]*im[r]) + 1e-8f;
      const int basei = 64*((r+4)&7);
      mo[basei + lane] = m;
      float wm = (wu == 2u) ? m + m : m;
      lsum += wm;
      lsq = fmaf(wm, m, lsq);
      lmn = fminf(lmn, m); lmx = fmaxf(lmx, m);
      atomicAdd(&hw[__float_as_uint(m) >> 23], wu);
      lq[QA[r]] += m;
      if (wu == 2u){
        if ((r & 1) == 0){
          float m0 = (lane == 0) ? m : 0.f;
          lq[QBM[r]] += m - m0;
          lq[(QBM[r]+1)&3] += m0;
        } else {
          lq[QBM[r]] += m;
        }
      }
    }
    float r0 = wredf(lsum), r1 = wredf(lsq);
    float r2 = wredf(lq[0]), r3 = wredf(lq[1]), r4 = wredf(lq[2]), r5 = wredf(lq[3]);
    float fmn = wred_min(lmn), fmx = wred_max(lmx);
    if (lane == 0){
      buff[0][wv]=r0; buff[1][wv]=r1; buff[2][wv]=r2;
      buff[3][wv]=r3; buff[4][wv]=r4; buff[5][wv]=r5;
      buff[6][wv]=fmn; buff[7][wv]=fmx;
    }
  }
  __syncthreads();
  int nact = 257 - j0; if (nact > 8) nact = 8;
  if (t == 0){
    double s0=0,s1=0,s2=0,s3=0,s4=0,s5=0; float mn=3.4e38f, mx=0.f;
    for (int i = 0; i < nact; ++i){
      s0+=(double)buff[0][i]; s1+=(double)buff[1][i]; s2+=(double)buff[2][i];
      s3+=(double)buff[3][i]; s4+=(double)buff[4][i]; s5+=(double)buff[5][i];
      mn=fminf(mn,buff[6][i]); mx=fmaxf(mx,buff[7][i]);
    }
    atomicAdd(sum + b, s0);
    atomicAdd(sumsq + b, s1);
    atomicAdd(qsum + b*4 + 0, s2);
    atomicAdd(qsum + b*4 + 1, s3);
    atomicAdd(qsum + b*4 + 2, s4);
    atomicAdd(qsum + b*4 + 3, s5);
    atomicMin(dmin + b, __float_as_uint(mn));
    atomicMax(dmax + b, __float_as_uint(mx));
  }
  unsigned* hb = hist1 + (size_t)b*256;
  if (t < 256){
    unsigned c = h[t] + h[256+t] + h[512+t] + h[768+t]
               + h[1024+t] + h[1280+t] + h[1536+t] + h[1792+t];
    if (c) atomicAdd(&hb[t], c);
  }
}

// ---------------- pass2: fine mantissa hist (8192 bins) + counts ----------------
// grid (BB, 16): y=0 covers 17 cols, y>0 cover 16 cols. 32 KB LDS hist ->
// 4 blocks/CU, 16 waves/CU (vs 1 block/CU before). Zero-skip global atomic merge.
__global__ __launch_bounds__(256) void pass2_kernel(const float4* __restrict__ magc4,
    const unsigned* __restrict__ hist1, const double* __restrict__ sum,
    const unsigned* __restrict__ dmax,
    unsigned* __restrict__ hist2, unsigned* __restrict__ cnt_gtm,
    unsigned* __restrict__ cnt_half, unsigned* __restrict__ cnt_tenth)
{
  __shared__ __align__(16) unsigned h[NFINE];
  __shared__ unsigned part[256];
  __shared__ unsigned rb[3][4];
  __shared__ unsigned s_sel;
  int t = threadIdx.x, b = blockIdx.x;
  {
    uint4 z = make_uint4(0u,0u,0u,0u);
    for (int i = t; i < NFINE/4; i += 256) ((uint4*)h)[i] = z;
  }
  const unsigned* hb1 = hist1 + (size_t)b*256;
  part[t] = hb1[t];
  __syncthreads();
  if (t == 0){
    unsigned target = MED_K, cum = 0; int bin = 0;
    for (; bin < 256; ++bin){ if (cum + part[bin] >= target) break; cum += part[bin]; }
    s_sel = (unsigned)bin;
  }
  __syncthreads();
  unsigned s1 = s_sel;
  float meanf = (float)(sum[b] / (double)NPIX);
  float d = __uint_as_float(dmax[b]) + 1e-8f;
  float th = 0.5f*d, tl = 0.1f*d;
  int y = blockIdx.y;
  int c_lo = (y == 0) ? 0 : 16*y + 1;
  int ncols = (y == 0) ? 17 : 16;
  const float4* p = magc4 + (size_t)b*(MAGB/4) + (size_t)c_lo*128;
  unsigned lgm = 0, lh = 0, lt = 0;
  int n4 = ncols * 128;
  for (int idx = t; idx < n4; idx += 256){
    float4 v = p[idx];
    int col = c_lo + (idx >> 7);
    unsigned w = (col == 0 || col == 256) ? 1u : 2u;
    float a[4] = {v.x, v.y, v.z, v.w};
    #pragma unroll
    for (int q = 0; q < 4; ++q){
      float m = a[q];
      unsigned bits = __float_as_uint(m);
      if ((bits >> 23) == s1) atomicAdd(&h[(bits >> 10) & 0x1fffu], w);
      lgm += (m > meanf) ? w : 0u;
      lh  += (m > th) ? w : 0u;
      lt  += (m > tl) ? w : 0u;
    }
  }
  int lane = t & 63, wv = t >> 6;
  unsigned g0 = wred_addu(lgm), g1 = wred_addu(lh), g2 = wred_addu(lt);
  if (lane == 0){ rb[0][wv]=g0; rb[1][wv]=g1; rb[2][wv]=g2; }
  __syncthreads();
  if (t == 0){
    unsigned a0=0,a1=0,a2=0;
    for (int i = 0; i < 4; ++i){ a0+=rb[0][i]; a1+=rb[1][i]; a2+=rb[2][i]; }
    atomicAdd(cnt_gtm + b, a0);
    atomicAdd(cnt_half + b, a1);
    atomicAdd(cnt_tenth + b, a2);
  }
  // zero-skip global atomic merge into per-image 8192-bin hist
  unsigned* hb = hist2 + (size_t)b*NFINE;
  for (int i = t; i < NFINE; i += 256){
    unsigned c = h[i];
    if (c) atomicAdd(&hb[i], c);
  }
}

// ---------------- scan2 + feats fused ----------------
__global__ __launch_bounds__(256) void scan2_feats_kernel(
    const unsigned* __restrict__ hist1, const unsigned* __restrict__ hist2,
    const unsigned* __restrict__ dmax, const unsigned* __restrict__ dmin,
    const double* __restrict__ sum, const double* __restrict__ sumsq,
    const double* __restrict__ qsum,
    const unsigned* __restrict__ cnt_half, const unsigned* __restrict__ cnt_tenth,
    const unsigned* __restrict__ cnt_gtmean,
    float* __restrict__ feats)
{
  int b = blockIdx.x, t = threadIdx.x;
  __shared__ __align__(16) unsigned hsum[NFINE];
  __shared__ unsigned part[256];
  __shared__ unsigned s_sel, s_rem;
  const uint4* h0 = (const uint4*)(hist2 + (size_t)b*NFINE);
  for (int i = t; i < NFINE/4; i += 256)
    ((uint4*)hsum)[i] = h0[i];
  const unsigned* hb1 = hist1 + (size_t)b*256;
  part[t] = hb1[t];
  __syncthreads();
  if (t == 0){
    unsigned target = MED_K, cum = 0; int bin = 0;
    for (; bin < 256; ++bin){ if (cum + part[bin] >= target) break; cum += part[bin]; }
    s_sel = (unsigned)bin; s_rem = target - cum;
  }
  __syncthreads();
  {
    // 256 segments of 32 bins
    unsigned sp = 0;
    int basei = t*32;
    for (int i = 0; i < 32; ++i) sp += hsum[basei + ((i + t) & 31)];
    part[t] = sp;
  }
  __syncthreads();
  if (t == 0){
    unsigned target = s_rem, cum = 0; int seg = 0;
    for (; seg < 256; ++seg){ if (cum + part[seg] >= target) break; cum += part[seg]; }
    unsigned r = target - cum;
    int bin = seg*32;
    for (;; ++bin){ unsigned c = hsum[bin]; if (c >= r) break; r -= c; }
    unsigned medbits = (s_sel << 23) | ((unsigned)bin << 10) | 512u;  // mantissa midpoint
    float maxv = __uint_as_float(dmax[b]);
    float dd_f = maxv + 1e-8f;
    double dd = (double)dd_f;
    double n = (double)NPIX;
    double sm = sum[b] / dd;
    double sq = sumsq[b] / (dd*dd);
    double mean = sm / n;
    double var = (sq - sm*sm/n) / (n - 1.0);
    if (var < 0.0) var = 0.0;
    float stdv = (float)sqrt(var);
    if (stdv < 1e-8f) stdv = 1e-8f;
    float f[12];
    f[0] = (float)mean;
    f[1] = stdv;
    f[2] = maxv / dd_f;
    f[3] = __uint_as_float(dmin[b]) / dd_f;
    f[4] = (float)((double)cnt_gtmean[b] / n);
    f[5] = __uint_as_float(medbits) / dd_f;
    f[6] = (float)(qsum[b*4+0] / dd * (1.0/65536.0));
    f[7] = (float)(qsum[b*4+1] / dd * (1.0/65536.0));
    f[8] = (float)(qsum[b*4+2] / dd * (1.0/65536.0));
    f[9] = (float)(qsum[b*4+3] / dd * (1.0/65536.0));
    f[10] = (float)((double)cnt_half[b] / n);
    f[11] = (float)((double)cnt_tenth[b] / n);
    #pragma unroll
    for (int i = 0; i < 12; ++i)
      feats[b*12 + i] = fminf(fmaxf(f[i], -10.f), 10.f);
  }
}

// ---------------- MLP layers 1+2 fused: one block, h1 stays in LDS ----------------
__global__ __launch_bounds__(512) void mlp12_kernel(const float* __restrict__ feats,
    const float* __restrict__ W1, const float* __restrict__ b1,
    const float* __restrict__ g1, const float* __restrict__ be1,
    const float* __restrict__ W2, const float* __restrict__ b2,
    const float* __restrict__ g2, const float* __restrict__ be2,
    float* __restrict__ h2t)
{
  __shared__ float h1[64*64];      // [col][row]
  int t = threadIdx.x, lane = t & 63, wv = t >> 6;
  float f[12];
  #pragma unroll
  for (int k = 0; k < 12; ++k) f[k] = feats[lane*12 + k];
  #pragma unroll
  for (int i = 0; i < 8; ++i){
    int c = wv*8 + i;
    float acc = b1[c];
    #pragma unroll
    for (int k = 0; k < 12; ++k) acc += f[k] * W1[k*64 + c];
    float mu = wred_add_all(acc) * (1.f/BB);
    float dv = acc - mu;
    float var = wred_add_all(dv*dv) * (1.f/BB);
    float scv = g1[c] / sqrtf(var + 1e-5f);
    float v = dv*scv + be1[c];
    h1[c*64 + lane] = v > 0.f ? v : 0.f;
  }
  __syncthreads();
  #pragma unroll
  for (int i = 0; i < 16; ++i){
    int c = wv*16 + i;
    float acc = b2[c];
    #pragma unroll 4
    for (int k = 0; k < 64; ++k) acc += h1[k*64 + lane] * W2[k*128 + c];
    float mu = wred_add_all(acc) * (1.f/BB);
    float dv = acc - mu;
    float var = wred_add_all(dv*dv) * (1.f/BB);
    float scv = g2[c] / sqrtf(var + 1e-5f);
    float v = dv*scv + be2[c];
    h2t[c*BB + lane] = v > 0.f ? v : 0.f;
  }
}

__global__ __launch_bounds__(256) void mlp3_kernel(const float* __restrict__ h2t,
    const float* __restrict__ W3, const float* __restrict__ b3,
    float* __restrict__ out)
{
  int r = threadIdx.x & 63;
  int w = threadIdx.x >> 6;
  int c = blockIdx.x*4 + w;
  float acc = b3[c];
  #pragma unroll 4
  for (int k = 0; k < 128; ++k) acc += h2t[k*BB + r] * W3[k*512 + c];
  out[r*512 + c] = acc;
}

// ---------------- launch ----------------
extern "C" void kernel_launch(void* const* d_in, const int* in_sizes, int n_in,
                              void* d_out, int out_size, void* d_ws, size_t ws_size,
                              hipStream_t stream) {
  (void)in_sizes; (void)n_in; (void)out_size; (void)ws_size;
  const float* x   = (const float*)d_in[0];
  const float* W1  = (const float*)d_in[1];
  const float* b1  = (const float*)d_in[2];
  const float* g1  = (const float*)d_in[3];
  const float* be1 = (const float*)d_in[4];
  const float* W2  = (const float*)d_in[5];
  const float* b2  = (const float*)d_in[6];
  const float* g2  = (const float*)d_in[7];
  const float* be2 = (const float*)d_in[8];
  const float* W3  = (const float*)d_in[9];
  const float* b3  = (const float*)d_in[10];
  float* out = (float*)d_out;

  char* ws = (char*)d_ws;
  float2* bufc = (float2*)ws;                                      // 69.2 MB used
  float*  magc = (float*)(ws + 134217728);                         // col-major, 33.7 MB
  unsigned* hist1 = (unsigned*)(ws + 134217728 + 34078720);        // 168,296,448 (64 KB)
  unsigned* hist2 = (unsigned*)(ws + 168296448 + 65536);           // 168,361,984 (2 MB: 64*8192*4)
  char* sc = ws + 168361984 + 2097152;                             // 170,459,136
  unsigned* dmax      = (unsigned*)(sc + 0);
  unsigned* dmin      = (unsigned*)(sc + 256);
  double*   sum       = (double*)(sc + 512);
  double*   sumsq     = (double*)(sc + 1024);
  double*   qsum      = (double*)(sc + 1536);
  unsigned* cnt_half  = (unsigned*)(sc + 3584);
  unsigned* cnt_tenth = (unsigned*)(sc + 3840);
  unsigned* cnt_gtm   = (unsigned*)(sc + 4096);
  float*    feats     = (float*)(sc + 5120);
  float*    h2t       = (float*)(sc + 8192);            // 32 KB
  float2*   twg       = (float2*)(sc + 8192 + 32768);   // 2 KB

  hipMemsetAsync(hist1, 0, 65536 + 2097152, stream);   // hist1+hist2 contiguous

  init_kernel<<<1, 256, 0, stream>>>(twg, (unsigned*)sc);
  row_fft_kernel<<<BB*64, 256, 0, stream>>>(x, twg, bufc);
  col_fft_kernel<<<BB*33, 512, 0, stream>>>(bufc, twg, magc, dmax, dmin, sum, sumsq, qsum, hist1);
  pass2_kernel<<<dim3(BB, 16), 256, 0, stream>>>((const float4*)magc, hist1, sum, dmax,
      hist2, cnt_gtm, cnt_half, cnt_tenth);
  scan2_feats_kernel<<<BB, 256, 0, stream>>>(hist1, hist2, dmax, dmin, sum, sumsq, qsum,
      cnt_half, cnt_tenth, cnt_gtm, feats);
  mlp12_kernel<<<1, 512, 0, stream>>>(feats, W1, b1, g1, be1, W2, b2, g2, be2, h2t);
  mlp3_kernel<<<128, 256, 0, stream>>>(h2t, W3, b3, out);
}

// Round 6
// 428.015 us; speedup vs baseline: 1.1305x; 1.1305x over previous
//
#include <hip/hip_runtime.h>
#include <math.h>

#ifndef M_PI
#define M_PI 3.14159265358979323846
#endif

#define BB 64
#define HH 512
#define WW 512
#define NPIX (HH*WW)        // 262144
#define MED_K 131072u       // 1-indexed rank of (n-1)//2
#define MAGB 131584         // per-image magc floats: 257 cols * 512 rows (col-major)
#define BSTRIDE 264         // bufc row stride (float2), cols 0..256 valid
#define SS 520              // col staging stride (floats) per column

__device__ __forceinline__ float wredf(float v){
  #pragma unroll
  for (int o = 32; o > 0; o >>= 1) v += __shfl_down(v, o, 64);
  return v;
}
__device__ __forceinline__ float wred_min(float v){
  #pragma unroll
  for (int o = 32; o > 0; o >>= 1) v = fminf(v, __shfl_down(v, o, 64));
  return v;
}
__device__ __forceinline__ float wred_max(float v){
  #pragma unroll
  for (int o = 32; o > 0; o >>= 1) v = fmaxf(v, __shfl_down(v, o, 64));
  return v;
}
__device__ __forceinline__ unsigned wred_addu(unsigned v){
  #pragma unroll
  for (int o = 32; o > 0; o >>= 1) v += __shfl_down(v, o, 64);
  return v;
}
__device__ __forceinline__ float wred_add_all(float v){
  #pragma unroll
  for (int o = 32; o > 0; o >>= 1) v += __shfl_xor(v, o, 64);
  return v;
}

// Wave-parallel "smallest idx with cumsum(part[0..idx]) >= target" over 256 counts.
// Call from one full wave (lane = 0..63). Returns idx and rem = target - cum_before.
__device__ __forceinline__ void scan256_select(const unsigned* __restrict__ part,
                                               unsigned target, int lane,
                                               unsigned &idx, unsigned &rem){
  unsigned s[4];
  s[0] = part[4*lane+0]; s[1] = part[4*lane+1];
  s[2] = part[4*lane+2]; s[3] = part[4*lane+3];
  unsigned local = s[0]+s[1]+s[2]+s[3];
  unsigned incl = local;
  #pragma unroll
  for (int o = 1; o < 64; o <<= 1){
    unsigned y = __shfl_up(incl, o, 64);
    if (lane >= o) incl += y;
  }
  unsigned excl = incl - local;
  unsigned long long bal = __ballot(incl >= target);
  int win = __ffsll(bal) - 1;
  unsigned bin = 0, r = 0;
  if (lane == win){
    unsigned cum = excl; int q = 0;
    #pragma unroll
    for (; q < 3; ++q){ if (cum + s[q] >= target) break; cum += s[q]; }
    bin = (unsigned)(4*win + q); r = target - cum;
  }
  idx = __shfl(bin, win, 64);
  rem = __shfl(r, win, 64);
}

// ---------------- init: twiddles + scalar block ----------------
__global__ void init_kernel(float2* __restrict__ twg, unsigned* __restrict__ scal){
  int t = threadIdx.x;  // 256
  double a = -2.0 * M_PI * (double)t / 512.0;
  twg[t] = make_float2((float)cos(a), (float)sin(a));
  #pragma unroll
  for (int q = 0; q < 8; ++q){
    int w = t*8 + q;
    scal[w] = (w >= 64 && w < 128) ? 0xFFFFFFFFu : 0u;
  }
}

// Per-stage compact twiddle tables, concatenated in LDS:
// T_st[k] = twg[k << (9-st)], k in [0, 2^(st-1)), stage st = 2..9.
__device__ __forceinline__ void build_twid(float2* T, const float2* __restrict__ twg,
                                           int t, int nthr){
  for (int i = t; i < 510; i += nthr){
    int v = i + 2;
    int z = 31 - __clz(v);
    T[i] = twg[(v - (1 << z)) << (8 - z)];
  }
}

// One cross-lane butterfly stage in sign-folded FMA form.
__device__ __forceinline__ void bfly_stage(float (&re)[8], float (&im)[8],
                                           int d, float A, float B, float C, float D){
  #pragma unroll
  for (int r = 0; r < 8; ++r){
    float ore = __shfl_xor(re[r], d, 64);
    float oim = __shfl_xor(im[r], d, 64);
    float sre = re[r], sim = im[r];
    re[r] = A*sre + B*ore + C*sim + D*oim;
    im[r] = A*sim + B*oim - C*sre - D*ore;
  }
}

// Wave-resident 512-point radix-2 DIT FFT (see prior rounds for layout docs).
__device__ __forceinline__ void wave_fft512(float (&re)[8], float (&im)[8],
                                            const float2* T, int lane){
  { // stage 1
    float A = (lane & 1) ? -1.f : 1.f;
    #pragma unroll
    for (int r = 0; r < 8; ++r){
      float ore = __shfl_xor(re[r], 1, 64);
      float oim = __shfl_xor(im[r], 1, 64);
      re[r] = A*re[r] + ore;
      im[r] = A*im[r] + oim;
    }
  }
  #pragma unroll
  for (int st = 2; st <= 6; ++st){
    const int d = 1 << (st - 1);
    float2 w = T[((1 << (st - 1)) - 2) + (lane & (d - 1))];
    bool hi = (lane & d) != 0;
    float A = hi ? -w.x : 1.f;
    float B = hi ? 1.f : w.x;
    float C = hi ? w.y : 0.f;
    float D = hi ? 0.f : -w.y;
    bfly_stage(re, im, d, A, B, C, D);
  }
  { // stage 7
    float2 w = T[62 + lane];
    #pragma unroll
    for (int r = 0; r < 8; r += 2){
      float vr = w.x*re[r+1] - w.y*im[r+1];
      float vi = w.x*im[r+1] + w.y*re[r+1];
      float ur = re[r], ui = im[r];
      re[r]   = ur + vr; im[r]   = ui + vi;
      re[r+1] = ur - vr; im[r+1] = ui - vi;
    }
  }
  { // stage 8
    float2 w0 = T[126 + lane];
    float2 w1 = T[190 + lane];
    #pragma unroll
    for (int rb = 0; rb < 8; rb += 4){
      {
        float vr = w0.x*re[rb+2] - w0.y*im[rb+2];
        float vi = w0.x*im[rb+2] + w0.y*re[rb+2];
        float ur = re[rb], ui = im[rb];
        re[rb]   = ur + vr; im[rb]   = ui + vi;
        re[rb+2] = ur - vr; im[rb+2] = ui - vi;
      }
      {
        float vr = w1.x*re[rb+3] - w1.y*im[rb+3];
        float vi = w1.x*im[rb+3] + w1.y*re[rb+3];
        float ur = re[rb+1], ui = im[rb+1];
        re[rb+1] = ur + vr; im[rb+1] = ui + vi;
        re[rb+3] = ur - vr; im[rb+3] = ui - vi;
      }
    }
  }
  { // stage 9
    #pragma unroll
    for (int r = 0; r < 4; ++r){
      float2 w = T[254 + 64*r + lane];
      float vr = w.x*re[r+4] - w.y*im[r+4];
      float vi = w.x*im[r+4] + w.y*re[r+4];
      float ur = re[r], ui = im[r];
      re[r]   = ur + vr; im[r]   = ui + vi;
      re[r+4] = ur - vr; im[r+4] = ui - vi;
    }
  }
}

// ---------------- row FFT: contiguous loads + shfl bit-reversal ----------------
__global__ __launch_bounds__(256) void row_fft_kernel(const float* __restrict__ x,
                                                      const float2* __restrict__ twg,
                                                      float2* __restrict__ out){
  __shared__ float2 T[510];
  int t = threadIdx.x;
  build_twid(T, twg, t, 256);
  __syncthreads();
  int lane = t & 63, wv = t >> 6;
  int pair = blockIdx.x*4 + wv;        // b*256 + hp
  int b = pair >> 8, hp = pair & 255;
  int c0 = lane << 3;
  const float* p0 = x + (size_t)b*3*NPIX + (size_t)(2*hp)*WW + c0;
  const float* p1 = p0 + WW;
  float4 ra0 = *(const float4*)(p0);          float4 ra1 = *(const float4*)(p0+4);
  float4 ga0 = *(const float4*)(p0+NPIX);     float4 ga1 = *(const float4*)(p0+NPIX+4);
  float4 ba0 = *(const float4*)(p0+2*NPIX);   float4 ba1 = *(const float4*)(p0+2*NPIX+4);
  float4 rb0 = *(const float4*)(p1);          float4 rb1 = *(const float4*)(p1+4);
  float4 gb0 = *(const float4*)(p1+NPIX);     float4 gb1 = *(const float4*)(p1+NPIX+4);
  float4 bb0 = *(const float4*)(p1+2*NPIX);   float4 bb1 = *(const float4*)(p1+2*NPIX+4);
  float g0[8] = {0.299f*ra0.x + 0.587f*ga0.x + 0.114f*ba0.x,
                 0.299f*ra0.y + 0.587f*ga0.y + 0.114f*ba0.y,
                 0.299f*ra0.z + 0.587f*ga0.z + 0.114f*ba0.z,
                 0.299f*ra0.w + 0.587f*ga0.w + 0.114f*ba0.w,
                 0.299f*ra1.x + 0.587f*ga1.x + 0.114f*ba1.x,
                 0.299f*ra1.y + 0.587f*ga1.y + 0.114f*ba1.y,
                 0.299f*ra1.z + 0.587f*ga1.z + 0.114f*ba1.z,
                 0.299f*ra1.w + 0.587f*ga1.w + 0.114f*ba1.w};
  float g1[8] = {0.299f*rb0.x + 0.587f*gb0.x + 0.114f*bb0.x,
                 0.299f*rb0.y + 0.587f*gb0.y + 0.114f*bb0.y,
                 0.299f*rb0.z + 0.587f*gb0.z + 0.114f*bb0.z,
                 0.299f*rb0.w + 0.587f*gb0.w + 0.114f*bb0.w,
                 0.299f*rb1.x + 0.587f*gb1.x + 0.114f*bb1.x,
                 0.299f*rb1.y + 0.587f*gb1.y + 0.114f*bb1.y,
                 0.299f*rb1.z + 0.587f*gb1.z + 0.114f*bb1.z,
                 0.299f*rb1.w + 0.587f*gb1.w + 0.114f*bb1.w};
  int src = (int)(__brev((unsigned)lane) >> 26);   // rev6(lane)
  float re[8], im[8];
  re[0] = __shfl(g0[0], src, 64); re[1] = __shfl(g0[4], src, 64);
  re[2] = __shfl(g0[2], src, 64); re[3] = __shfl(g0[6], src, 64);
  re[4] = __shfl(g0[1], src, 64); re[5] = __shfl(g0[5], src, 64);
  re[6] = __shfl(g0[3], src, 64); re[7] = __shfl(g0[7], src, 64);
  im[0] = __shfl(g1[0], src, 64); im[1] = __shfl(g1[4], src, 64);
  im[2] = __shfl(g1[2], src, 64); im[3] = __shfl(g1[6], src, 64);
  im[4] = __shfl(g1[1], src, 64); im[5] = __shfl(g1[5], src, 64);
  im[6] = __shfl(g1[3], src, 64); im[7] = __shfl(g1[7], src, 64);
  wave_fft512(re, im, T, lane);
  int row0 = (b << 9) + 2*hp;
  float2* o0 = out + (size_t)row0*BSTRIDE;
  float2* o1 = o0 + BSTRIDE;
  int srcl = (64 - lane) & 63;
  float p4r = __shfl(re[4], srcl, 64), p4i = __shfl(im[4], srcl, 64);
  float p5r = __shfl(re[5], srcl, 64), p5i = __shfl(im[5], srcl, 64);
  float p6r = __shfl(re[6], srcl, 64), p6i = __shfl(im[6], srcl, 64);
  float p7r = __shfl(re[7], srcl, 64), p7i = __shfl(im[7], srcl, 64);
  bool l0 = (lane == 0);
  {
    float zr = re[0], zi = im[0];
    float wr = l0 ? re[0] : p7r, wi = l0 ? im[0] : p7i;
    o0[lane] = make_float2(0.5f*(zr + wr), 0.5f*(zi - wi));
    o1[lane] = make_float2(0.5f*(zi + wi), 0.5f*(wr - zr));
  }
  {
    float zr = re[1], zi = im[1];
    float wr = l0 ? re[7] : p6r, wi = l0 ? im[7] : p6i;
    int k = lane + 64;
    o0[k] = make_float2(0.5f*(zr + wr), 0.5f*(zi - wi));
    o1[k] = make_float2(0.5f*(zi + wi), 0.5f*(wr - zr));
  }
  {
    float zr = re[2], zi = im[2];
    float wr = l0 ? re[6] : p5r, wi = l0 ? im[6] : p5i;
    int k = lane + 128;
    o0[k] = make_float2(0.5f*(zr + wr), 0.5f*(zi - wi));
    o1[k] = make_float2(0.5f*(zi + wi), 0.5f*(wr - zr));
  }
  {
    float zr = re[3], zi = im[3];
    float wr = l0 ? re[5] : p4r, wi = l0 ? im[5] : p4i;
    int k = lane + 192;
    o0[k] = make_float2(0.5f*(zr + wr), 0.5f*(zi - wi));
    o1[k] = make_float2(0.5f*(zi + wi), 0.5f*(wr - zr));
  }
  if (l0){
    float zr = re[4], zi = im[4];
    o0[256] = make_float2(zr, 0.f);
    o1[256] = make_float2(zi, 0.f);
  }
}

// ---------------- col FFT: wave-per-column register FFT + fused stats ----------------
__global__ __launch_bounds__(512) void col_fft_kernel(const float2* __restrict__ in,
    const float2* __restrict__ twg,
    float* __restrict__ magc,
    unsigned* __restrict__ dmax, unsigned* __restrict__ dmin,
    double* __restrict__ sum, double* __restrict__ sumsq, double* __restrict__ qsum,
    unsigned* __restrict__ hist1)
{
  __shared__ float st_re[8*SS];
  __shared__ float st_im[8*SS];
  __shared__ float2 T[510];
  __shared__ unsigned h[8*256];       // per-wave privatized exponent histogram
  __shared__ float buff[8][8];
  int t = threadIdx.x;
  int lane = t & 63, wv = t >> 6;
  build_twid(T, twg, t, 512);
  for (int i = t; i < 2048; i += 512) h[i] = 0u;
  int b = blockIdx.x / 33;
  int j0 = (blockIdx.x % 33) << 3;
  const float2* base = in + (size_t)b * (size_t)(512*BSTRIDE);
  #pragma unroll
  for (int it = 0; it < 8; ++it){
    int idx = t + (it << 9);
    int e = idx >> 3, jj = idx & 7;
    float2 v = base[(size_t)e*BSTRIDE + j0 + jj];
    int se = e ^ (e >> 3);
    st_re[jj*SS + se] = v.x;
    st_im[jj*SS + se] = v.y;
  }
  __syncthreads();
  int j = j0 + wv;
  if (j <= 256){
    int K = (int)(__brev((unsigned)lane) >> 26);   // rev6(lane)
    const int rv3[8] = {0,4,2,6,1,5,3,7};
    float re[8], im[8];
    #pragma unroll
    for (int r = 0; r < 8; ++r){
      int e = 8*K + rv3[r];
      int se = e ^ K;
      re[r] = st_re[wv*SS + se];
      im[r] = st_im[wv*SS + se];
    }
    wave_fft512(re, im, T, lane);
    unsigned wu = (j == 0 || j == 256) ? 1u : 2u;
    float* mo = magc + (size_t)b*MAGB + (size_t)j*512;
    unsigned* hw = h + (wv << 8);
    float lsum=0.f, lsq=0.f;
    float lq[4] = {0.f, 0.f, 0.f, 0.f};
    float lmn = 3.4e38f, lmx = 0.f;
    const int QA[8]  = {2,2,3,3,0,0,1,1};
    const int QBM[8] = {1,1,0,0,3,3,2,2};
    #pragma unroll
    for (int r = 0; r < 8; ++r){
      float m = sqrtf(re[r]*re[r] + im[r]*im[r]) + 1e-8f;
      const int basei = 64*((r+4)&7);
      mo[basei + lane] = m;
      float wm = (wu == 2u) ? m + m : m;
      lsum += wm;
      lsq = fmaf(wm, m, lsq);
      lmn = fminf(lmn, m); lmx = fmaxf(lmx, m);
      atomicAdd(&hw[__float_as_uint(m) >> 23], wu);
      lq[QA[r]] += m;
      if (wu == 2u){
        if ((r & 1) == 0){
          float m0 = (lane == 0) ? m : 0.f;
          lq[QBM[r]] += m - m0;
          lq[(QBM[r]+1)&3] += m0;
        } else {
          lq[QBM[r]] += m;
        }
      }
    }
    float r0 = wredf(lsum), r1 = wredf(lsq);
    float r2 = wredf(lq[0]), r3 = wredf(lq[1]), r4 = wredf(lq[2]), r5 = wredf(lq[3]);
    float fmn = wred_min(lmn), fmx = wred_max(lmx);
    if (lane == 0){
      buff[0][wv]=r0; buff[1][wv]=r1; buff[2][wv]=r2;
      buff[3][wv]=r3; buff[4][wv]=r4; buff[5][wv]=r5;
      buff[6][wv]=fmn; buff[7][wv]=fmx;
    }
  }
  __syncthreads();
  int nact = 257 - j0; if (nact > 8) nact = 8;
  if (t == 0){
    double s0=0,s1=0,s2=0,s3=0,s4=0,s5=0; float mn=3.4e38f, mx=0.f;
    for (int i = 0; i < nact; ++i){
      s0+=(double)buff[0][i]; s1+=(double)buff[1][i]; s2+=(double)buff[2][i];
      s3+=(double)buff[3][i]; s4+=(double)buff[4][i]; s5+=(double)buff[5][i];
      mn=fminf(mn,buff[6][i]); mx=fmaxf(mx,buff[7][i]);
    }
    atomicAdd(sum + b, s0);
    atomicAdd(sumsq + b, s1);
    atomicAdd(qsum + b*4 + 0, s2);
    atomicAdd(qsum + b*4 + 1, s3);
    atomicAdd(qsum + b*4 + 2, s4);
    atomicAdd(qsum + b*4 + 3, s5);
    atomicMin(dmin + b, __float_as_uint(mn));
    atomicMax(dmax + b, __float_as_uint(mx));
  }
  unsigned* hb = hist1 + (size_t)b*256;
  if (t < 256){
    unsigned c = h[t] + h[256+t] + h[512+t] + h[768+t]
               + h[1024+t] + h[1280+t] + h[1536+t] + h[1792+t];
    if (c) atomicAdd(&hb[t], c);
  }
}

// ---------------- pass2: fine mantissa hist (per-slice, no atomics) + counts ----------------
// grid (BB, 4); y-block covers cols [y*65, min(257, y*65+65)).
// hist2 layout: [b][slice(4)][16384] — each block streams its own slice.
__global__ __launch_bounds__(256) void pass2_kernel(const float4* __restrict__ magc4,
    const unsigned* __restrict__ hist1, const double* __restrict__ sum,
    const unsigned* __restrict__ dmax,
    unsigned* __restrict__ hist2, unsigned* __restrict__ cnt_gtm,
    unsigned* __restrict__ cnt_half, unsigned* __restrict__ cnt_tenth)
{
  __shared__ __align__(16) unsigned h[16384];
  __shared__ unsigned part[256];
  __shared__ unsigned rb[3][4];
  __shared__ unsigned s_sel;
  int t = threadIdx.x, b = blockIdx.x;
  {
    uint4 z = make_uint4(0u,0u,0u,0u);
    for (int i = t; i < 4096; i += 256) ((uint4*)h)[i] = z;
  }
  const unsigned* hb1 = hist1 + (size_t)b*256;
  part[t] = hb1[t];
  __syncthreads();
  if (t < 64){
    unsigned selv, remv;
    scan256_select(part, MED_K, t, selv, remv);
    if (t == 0) s_sel = selv;
  }
  __syncthreads();
  unsigned s1 = s_sel;
  float meanf = (float)(sum[b] / (double)NPIX);
  float d = __uint_as_float(dmax[b]) + 1e-8f;
  float th = 0.5f*d, tl = 0.1f*d;
  int c_lo = blockIdx.y * 65;
  int ncols = 257 - c_lo; if (ncols > 65) ncols = 65;
  const float4* p = magc4 + (size_t)b*(MAGB/4) + (size_t)c_lo*128;
  unsigned lgm = 0, lh = 0, lt = 0;
  int n4 = ncols * 128;
  for (int idx = t; idx < n4; idx += 256){
    float4 v = p[idx];
    int col = c_lo + (idx >> 7);
    unsigned w = (col == 0 || col == 256) ? 1u : 2u;
    float a[4] = {v.x, v.y, v.z, v.w};
    #pragma unroll
    for (int q = 0; q < 4; ++q){
      float m = a[q];
      unsigned bits = __float_as_uint(m);
      if ((bits >> 23) == s1) atomicAdd(&h[(bits >> 9) & 0x3fffu], w);
      lgm += (m > meanf) ? w : 0u;
      lh  += (m > th) ? w : 0u;
      lt  += (m > tl) ? w : 0u;
    }
  }
  int lane = t & 63, wv = t >> 6;
  unsigned g0 = wred_addu(lgm), g1 = wred_addu(lh), g2 = wred_addu(lt);
  if (lane == 0){ rb[0][wv]=g0; rb[1][wv]=g1; rb[2][wv]=g2; }
  __syncthreads();
  if (t == 0){
    unsigned a0=0,a1=0,a2=0;
    for (int i = 0; i < 4; ++i){ a0+=rb[0][i]; a1+=rb[1][i]; a2+=rb[2][i]; }
    atomicAdd(cnt_gtm + b, a0);
    atomicAdd(cnt_half + b, a1);
    atomicAdd(cnt_tenth + b, a2);
  }
  // plain streamed store of this block's slice (no global atomics)
  unsigned* hb = hist2 + (((size_t)b*4) + blockIdx.y)*16384;
  for (int i = t; i < 4096; i += 256)
    ((uint4*)hb)[i] = ((const uint4*)h)[i];
}

// ---------------- scan2 + feats fused (slice-sum in LDS, wave-parallel scans) ----------------
__global__ __launch_bounds__(256) void scan2_feats_kernel(
    const unsigned* __restrict__ hist1, const unsigned* __restrict__ hist2,
    const unsigned* __restrict__ dmax, const unsigned* __restrict__ dmin,
    const double* __restrict__ sum, const double* __restrict__ sumsq,
    const double* __restrict__ qsum,
    const unsigned* __restrict__ cnt_half, const unsigned* __restrict__ cnt_tenth,
    const unsigned* __restrict__ cnt_gtmean,
    float* __restrict__ feats)
{
  int b = blockIdx.x, t = threadIdx.x;
  __shared__ __align__(16) unsigned hsum[16384];
  __shared__ unsigned part[256];
  __shared__ unsigned s_sel, s_rem;
  // sum the 4 per-slice fine hists into LDS
  const uint4* h0 = (const uint4*)(hist2 + (size_t)b*4*16384);
  for (int i = t; i < 4096; i += 256){
    uint4 a = h0[i], c = h0[4096 + i], d2 = h0[8192 + i], e = h0[12288 + i];
    uint4 s;
    s.x = a.x + c.x + d2.x + e.x;
    s.y = a.y + c.y + d2.y + e.y;
    s.z = a.z + c.z + d2.z + e.z;
    s.w = a.w + c.w + d2.w + e.w;
    ((uint4*)hsum)[i] = s;
  }
  const unsigned* hb1 = hist1 + (size_t)b*256;
  part[t] = hb1[t];
  __syncthreads();
  if (t < 64){
    unsigned selv, remv;
    scan256_select(part, MED_K, t, selv, remv);
    if (t == 0){ s_sel = selv; s_rem = remv; }
  }
  __syncthreads();
  {
    // segment sums from LDS; rotated start avoids bank aliasing
    unsigned sp = 0;
    int basei = t*64;
    for (int i = 0; i < 64; ++i) sp += hsum[basei + ((i + t) & 63)];
    part[t] = sp;
  }
  __syncthreads();
  if (t < 64){
    unsigned seg, rem2;
    scan256_select(part, s_rem, t, seg, rem2);
    // parallel in-segment walk: lanes hold the 64 bins of the segment
    unsigned c = hsum[seg*64 + t];
    unsigned incl = c;
    #pragma unroll
    for (int o = 1; o < 64; o <<= 1){
      unsigned y = __shfl_up(incl, o, 64);
      if (t >= o) incl += y;
    }
    unsigned long long bal = __ballot(incl >= rem2);
    int win = __ffsll(bal) - 1;
    int bin = (int)seg*64 + win;        // uniform across lanes
    if (t == 0){
      unsigned medbits = (s_sel << 23) | ((unsigned)bin << 9) | 256u;  // mantissa midpoint
      float maxv = __uint_as_float(dmax[b]);
      float dd_f = maxv + 1e-8f;
      double dd = (double)dd_f;
      double n = (double)NPIX;
      double sm = sum[b] / dd;
      double sq = sumsq[b] / (dd*dd);
      double mean = sm / n;
      double var = (sq - sm*sm/n) / (n - 1.0);
      if (var < 0.0) var = 0.0;
      float stdv = (float)sqrt(var);
      if (stdv < 1e-8f) stdv = 1e-8f;
      float f[12];
      f[0] = (float)mean;
      f[1] = stdv;
      f[2] = maxv / dd_f;
      f[3] = __uint_as_float(dmin[b]) / dd_f;
      f[4] = (float)((double)cnt_gtmean[b] / n);
      f[5] = __uint_as_float(medbits) / dd_f;
      f[6] = (float)(qsum[b*4+0] / dd * (1.0/65536.0));
      f[7] = (float)(qsum[b*4+1] / dd * (1.0/65536.0));
      f[8] = (float)(qsum[b*4+2] / dd * (1.0/65536.0));
      f[9] = (float)(qsum[b*4+3] / dd * (1.0/65536.0));
      f[10] = (float)((double)cnt_half[b] / n);
      f[11] = (float)((double)cnt_tenth[b] / n);
      #pragma unroll
      for (int i = 0; i < 12; ++i)
        feats[b*12 + i] = fminf(fmaxf(f[i], -10.f), 10.f);
    }
  }
}

// ---------------- MLP: column-parallel, BN per-column in one wave ----------------
__global__ __launch_bounds__(64) void mlp1_kernel(const float* __restrict__ feats,
    const float* __restrict__ W1, const float* __restrict__ b1,
    const float* __restrict__ g1, const float* __restrict__ be1,
    float* __restrict__ h1t)
{
  int c = blockIdx.x, r = threadIdx.x;
  float acc = b1[c];
  #pragma unroll
  for (int k = 0; k < 12; ++k) acc += feats[r*12 + k] * W1[k*64 + c];
  float mu = wred_add_all(acc) * (1.f/BB);
  float dv = acc - mu;
  float var = wred_add_all(dv*dv) * (1.f/BB);
  float scv = g1[c] / sqrtf(var + 1e-5f);
  float v = dv*scv + be1[c];
  h1t[c*BB + r] = v > 0.f ? v : 0.f;
}

__global__ __launch_bounds__(64) void mlp2_kernel(const float* __restrict__ h1t,
    const float* __restrict__ W2, const float* __restrict__ b2,
    const float* __restrict__ g2, const float* __restrict__ be2,
    float* __restrict__ h2t)
{
  int c = blockIdx.x, r = threadIdx.x;
  float acc = b2[c];
  #pragma unroll 4
  for (int k = 0; k < 64; ++k) acc += h1t[k*BB + r] * W2[k*128 + c];
  float mu = wred_add_all(acc) * (1.f/BB);
  float dv = acc - mu;
  float var = wred_add_all(dv*dv) * (1.f/BB);
  float scv = g2[c] / sqrtf(var + 1e-5f);
  float v = dv*scv + be2[c];
  h2t[c*BB + r] = v > 0.f ? v : 0.f;
}

__global__ __launch_bounds__(256) void mlp3_kernel(const float* __restrict__ h2t,
    const float* __restrict__ W3, const float* __restrict__ b3,
    float* __restrict__ out)
{
  int r = threadIdx.x & 63;
  int w = threadIdx.x >> 6;
  int c = blockIdx.x*4 + w;
  float acc = b3[c];
  #pragma unroll 4
  for (int k = 0; k < 128; ++k) acc += h2t[k*BB + r] * W3[k*512 + c];
  out[r*512 + c] = acc;
}

// ---------------- launch ----------------
extern "C" void kernel_launch(void* const* d_in, const int* in_sizes, int n_in,
                              void* d_out, int out_size, void* d_ws, size_t ws_size,
                              hipStream_t stream) {
  (void)in_sizes; (void)n_in; (void)out_size; (void)ws_size;
  const float* x   = (const float*)d_in[0];
  const float* W1  = (const float*)d_in[1];
  const float* b1  = (const float*)d_in[2];
  const float* g1  = (const float*)d_in[3];
  const float* be1 = (const float*)d_in[4];
  const float* W2  = (const float*)d_in[5];
  const float* b2  = (const float*)d_in[6];
  const float* g2  = (const float*)d_in[7];
  const float* be2 = (const float*)d_in[8];
  const float* W3  = (const float*)d_in[9];
  const float* b3  = (const float*)d_in[10];
  float* out = (float*)d_out;

  char* ws = (char*)d_ws;
  float2* bufc = (float2*)ws;                                      // 69.2 MB used
  float*  magc = (float*)(ws + 134217728);                         // col-major, 33.7 MB
  unsigned* hist1 = (unsigned*)(ws + 134217728 + 34078720);        // 168,296,448 (64 KB)
  unsigned* hist2 = (unsigned*)(ws + 168296448 + 65536);           // 168,361,984 (16 MB: 64*4*16384*4)
  char* sc = ws + 168361984 + 16777216;                            // 185,139,200
  unsigned* dmax      = (unsigned*)(sc + 0);
  unsigned* dmin      = (unsigned*)(sc + 256);
  double*   sum       = (double*)(sc + 512);
  double*   sumsq     = (double*)(sc + 1024);
  double*   qsum      = (double*)(sc + 1536);
  unsigned* cnt_half  = (unsigned*)(sc + 3584);
  unsigned* cnt_tenth = (unsigned*)(sc + 3840);
  unsigned* cnt_gtm   = (unsigned*)(sc + 4096);
  float*    feats     = (float*)(sc + 5120);
  float*    h1t       = (float*)(sc + 8192);            // 16 KB
  float*    h2t       = (float*)(sc + 8192 + 16384);    // 32 KB
  float2*   twg       = (float2*)(sc + 8192 + 16384 + 32768);  // 2 KB

  hipMemsetAsync(hist1, 0, 65536, stream);   // hist1 only; hist2 slices fully overwritten

  init_kernel<<<1, 256, 0, stream>>>(twg, (unsigned*)sc);
  row_fft_kernel<<<BB*64, 256, 0, stream>>>(x, twg, bufc);
  col_fft_kernel<<<BB*33, 512, 0, stream>>>(bufc, twg, magc, dmax, dmin, sum, sumsq, qsum, hist1);
  pass2_kernel<<<dim3(BB, 4), 256, 0, stream>>>((const float4*)magc, hist1, sum, dmax,
      hist2, cnt_gtm, cnt_half, cnt_tenth);
  scan2_feats_kernel<<<BB, 256, 0, stream>>>(hist1, hist2, dmax, dmin, sum, sumsq, qsum,
      cnt_half, cnt_tenth, cnt_gtm, feats);
  mlp1_kernel<<<64, 64, 0, stream>>>(feats, W1, b1, g1, be1, h1t);
  mlp2_kernel<<<128, 64, 0, stream>>>(h1t, W2, b2, g2, be2, h2t);
  mlp3_kernel<<<128, 256, 0, stream>>>(h2t, W3, b3, out);
}